// Round 12
// baseline (697.697 us; speedup 1.0000x reference)
//
#include <hip/hip_runtime.h>
#include <hip/hip_bf16.h>
#include <cstdio>

#define KQ   256
#define HID  128
typedef unsigned short u16;
#define SCALE_F 0.1767766952966369f  // 1/sqrt(32)

typedef __bf16 bf16x8 __attribute__((ext_vector_type(8)));
typedef short  s16x8  __attribute__((ext_vector_type(8)));
typedef float  f32x4  __attribute__((ext_vector_type(4)));

static __device__ __forceinline__ float bfu(u16 u) {
    return __uint_as_float(((unsigned)u) << 16);
}
static __device__ __forceinline__ u16 f2b(float f) {
    unsigned u = __float_as_uint(f);
    return (u16)((u + 0x7FFFu + ((u >> 16) & 1u)) >> 16);  // RNE
}
static __device__ __forceinline__ float ldf(const void* p, int i, int f) {
    return f ? ((const float*)p)[i] : bfu(((const u16*)p)[i]);
}
static __device__ __forceinline__ f32x4 mfma16(s16x8 a, s16x8 b, f32x4 c) {
    return __builtin_amdgcn_mfma_f32_16x16x32_bf16(
        __builtin_bit_cast(bf16x8, a), __builtin_bit_cast(bf16x8, b), c, 0, 0, 0);
}

// ---------------------------------------------------------------------------
// Workspace layout (f32 units) — unchanged from rounds 5/7/10/11 (passing).
// ---------------------------------------------------------------------------
#define OFF_WB     8256
#define OFF_LANGB  237632
#define OFF_ROWS   3383360
#define OFF_FEATSB 3387456
#define OFF_FAB    3649600
#define OFF_QB     7843904
#define OFF_KB     12038208
#define OFF_VB     16232512
#define OFF_MASK   20426816
#define NEEDF      20430912

#define WB_FCW1 0
#define WB_FCW2 147456
#define WB_SAWQ 163840
#define WB_SAWK 196608
#define WB_SAWV 229376
#define WB_SAWO 262144
#define WB_CAWQ 294912
#define WB_CAWK 327680
#define WB_CAWV 360448
#define WB_CAWO 393216
#define WB_MW1  425984
#define WB_MW2  442368

// ---------------------------------------------------------------------------
__global__ __launch_bounds__(256) void k_detect(
    const unsigned* __restrict__ onesw, const unsigned* __restrict__ maskw,
    int* __restrict__ flags)
{
    __shared__ int fb;
    if (threadIdx.x == 0) fb = 0;
    __syncthreads();
    int any = 0;
    for (int i = threadIdx.x; i < 4096; i += 256) any |= (maskw[i] > 1u) ? 1 : 0;
    if (any) atomicOr(&fb, 1);
    __syncthreads();
    if (threadIdx.x == 0) {
        flags[0] = (onesw[0] == 0x3F800000u) ? 1 : 0;
        flags[1] = fb;
    }
}

__global__ __launch_bounds__(256) void k_mask_canon(
    const unsigned char* __restrict__ raw, const int* __restrict__ flags,
    unsigned char* __restrict__ mask8)
{
    int i = blockIdx.x*256 + threadIdx.x;
    if (flags[1]) mask8[i] = raw[i] ? 1 : 0;
    else          mask8[i] = (((const unsigned int*)raw)[i] != 0u) ? 1 : 0;
}

// All bf16 conversions in ONE launch (verified passing rounds 10/11).
struct CvTab {
    const void* src[14];
    unsigned long long dst[14];   // u16 offset from U
    int bstart[15];
};
__global__ __launch_bounds__(256) void k_convAll(
    CvTab t, u16* __restrict__ U, const int* __restrict__ flags)
{
    int b = blockIdx.x;
    int e = 0;
    while (e < 13 && b >= t.bstart[e+1]) ++e;
    long long local = (long long)(b - t.bstart[e])*1024 + threadIdx.x*4;
    u16* dst = U + t.dst[e] + local;
    if (flags[0]) {
        float4 v = *((const float4*)t.src[e] + (local >> 2));
        ushort4 o; o.x = f2b(v.x); o.y = f2b(v.y); o.z = f2b(v.z); o.w = f2b(v.w);
        *(ushort4*)dst = o;
    } else {
        *(ushort4*)dst = *((const ushort4*)t.src[e] + (local >> 2));
    }
}

// ---------------------------------------------------------------------------
// Inverse row sums of 1/(d+0.01) (verified passing).
// ---------------------------------------------------------------------------
__global__ __launch_bounds__(256) void k_rowsum(
    const void* __restrict__ center, float* __restrict__ rsinv,
    const int* __restrict__ flags)
{
    int f  = flags[0];
    int bi = blockIdx.x, b = bi >> 8, j = threadIdx.x;
    float cx = ldf(center, bi*3+0, f), cy = ldf(center, bi*3+1, f), cz = ldf(center, bi*3+2, f);
    int pj = (b << 8) + j;
    float px = ldf(center, pj*3+0, f), py = ldf(center, pj*3+1, f), pz = ldf(center, pj*3+2, f);
    float dx = px-cx, dy = py-cy, dz = pz-cz;
    float d  = sqrtf(dx*dx + dy*dy + dz*dz);
    float w  = 1.f/(d + 0.01f);
    float sw = w;
    #pragma unroll
    for (int m = 32; m >= 1; m >>= 1) sw += __shfl_xor(sw, m);
    __shared__ float red[4];
    if ((j & 63) == 0) red[j >> 6] = sw;
    __syncthreads();
    if (j == 0) rsinv[bi] = 1.f / (red[0] + red[1] + red[2] + red[3]);
}

// ---------------------------------------------------------------------------
// MFMA GEMM (unchanged; EPI 0/1/3 still used).
// ---------------------------------------------------------------------------
template<int EPI, bool ABCAST, bool RBCAST>
__global__ __launch_bounds__(256) void k_gemm(
    const u16* __restrict__ A, const u16* __restrict__ W, u16* __restrict__ C,
    int Kd, const void* __restrict__ bias,
    const void* __restrict__ bng, const void* __restrict__ bnb,
    const void* __restrict__ bnm, const void* __restrict__ bnv,
    const void* __restrict__ pa,
    const void* __restrict__ lg, const void* __restrict__ lb,
    const u16* __restrict__ resid, const int* __restrict__ flags, int voff)
{
    __shared__ __align__(16) u16 Wl[128*136];
    int f = flags[0];
    int t = threadIdx.x, w = t>>6, lane = t&63, lm = lane&15, q4 = lane>>4;
    int m0 = blockIdx.x*64;
    int arow = m0 + w*16 + lm;
    int grow = ABCAST ? (((arow>>12)<<8)|(arow&255)) : arow;
    const u16* Abase = A + (size_t)grow*Kd;
    f32x4 acc[8];
    #pragma unroll
    for (int nt = 0; nt < 8; ++nt) acc[nt] = f32x4{0.f,0.f,0.f,0.f};
    int sr = t>>1, ss = (t&1)*64;
    for (int k0 = 0; k0 < Kd; k0 += 128) {
        const u16* src = W + (size_t)sr*Kd + k0 + ss;
        u16* dst = Wl + sr*136 + ss;
        #pragma unroll
        for (int i = 0; i < 8; ++i) *(s16x8*)(dst + i*8) = *(const s16x8*)(src + i*8);
        __syncthreads();
        s16x8 aF[4];
        #pragma unroll
        for (int ks = 0; ks < 4; ++ks) aF[ks] = *(const s16x8*)(Abase + k0 + ks*32 + q4*8);
        #pragma unroll
        for (int nt = 0; nt < 8; ++nt)
            #pragma unroll
            for (int ks = 0; ks < 4; ++ks) {
                s16x8 bF = *(const s16x8*)(Wl + (nt*16+lm)*136 + ks*32 + q4*8);
                acc[nt] = mfma16(aF[ks], bF, acc[nt]);
            }
        __syncthreads();
    }
    int row = m0 + w*16 + q4*4;
    if (EPI == 3) {
        float xs[8][4];
        #pragma unroll
        for (int nt = 0; nt < 8; ++nt) {
            int ch = nt*16 + lm;
            float bs = ldf(bias, voff + ch, f);
            #pragma unroll
            for (int r = 0; r < 4; ++r) {
                int rr = row + r;
                int rrow = RBCAST ? (((rr>>12)<<8)|(rr&255)) : rr;
                xs[nt][r] = acc[nt][r] + bs + bfu(resid[(size_t)rrow*HID + ch]);
            }
        }
        #pragma unroll
        for (int r = 0; r < 4; ++r) {
            float sm = 0.f, sq = 0.f;
            #pragma unroll
            for (int nt = 0; nt < 8; ++nt) { sm += xs[nt][r]; sq += xs[nt][r]*xs[nt][r]; }
            #pragma unroll
            for (int d = 1; d <= 8; d <<= 1) { sm += __shfl_xor(sm, d); sq += __shfl_xor(sq, d); }
            float mean = sm * (1.f/128.f);
            float var  = sq * (1.f/128.f) - mean*mean;
            float rs   = rsqrtf(var + 1e-5f);
            #pragma unroll
            for (int nt = 0; nt < 8; ++nt) {
                int ch = nt*16 + lm;
                float g = ldf(lg, voff + ch, f), bb = ldf(lb, voff + ch, f);
                C[(size_t)(row+r)*HID + ch] = f2b((xs[nt][r]-mean)*rs*g + bb);
            }
        }
    } else {
        #pragma unroll
        for (int nt = 0; nt < 8; ++nt) {
            int ch = nt*16 + lm;
            float bs = ldf(bias, voff + ch, f);
            float scl = 1.f, sh = 0.f, al = 0.f;
            if (EPI >= 1) {
                float g  = ldf(bng, ch, f), bb = ldf(bnb, ch, f);
                float mn = ldf(bnm, ch, f), vv = ldf(bnv, ch, f);
                scl = g * rsqrtf(vv + 1e-5f);
                sh  = bb - mn*scl;
                al  = ldf(pa, ch, f);
            }
            #pragma unroll
            for (int r = 0; r < 4; ++r) {
                float x = acc[nt][r] + bs;
                if (EPI >= 1) { x = x*scl + sh; x = (x >= 0.f) ? x : al*x; }
                C[(size_t)(row+r)*HID + ch] = f2b(x);
            }
        }
    }
}

// ---------------------------------------------------------------------------
// Triple-output GEMM (unchanged — passing).
// ---------------------------------------------------------------------------
template<bool ABCAST>
__global__ __launch_bounds__(256) void k_gemmN(
    const u16* __restrict__ A,
    const u16* __restrict__ W0, const u16* __restrict__ W1, const u16* __restrict__ W2,
    u16* __restrict__ C0, u16* __restrict__ C1, u16* __restrict__ C2,
    const void* __restrict__ b0, const void* __restrict__ b1, const void* __restrict__ b2,
    const int* __restrict__ flags, int voff)
{
    __shared__ __align__(16) u16 Wl[128*136];
    int y = blockIdx.y;
    const u16* W = (y == 0) ? W0 : (y == 1) ? W1 : W2;
    u16* C = (y == 0) ? C0 : (y == 1) ? C1 : C2;
    const void* bias = (y == 0) ? b0 : (y == 1) ? b1 : b2;
    int f = flags[0];
    int t = threadIdx.x, w = t>>6, lane = t&63, lm = lane&15, q4 = lane>>4;
    int m0 = blockIdx.x*64;
    int arow = m0 + w*16 + lm;
    int grow = ABCAST ? (((arow>>12)<<8)|(arow&255)) : arow;
    const u16* Abase = A + (size_t)grow*128;
    f32x4 acc[8];
    #pragma unroll
    for (int nt = 0; nt < 8; ++nt) acc[nt] = f32x4{0.f,0.f,0.f,0.f};
    int sr = t>>1, ss = (t&1)*64;
    {
        const u16* src = W + (size_t)sr*128 + ss;
        u16* dst = Wl + sr*136 + ss;
        #pragma unroll
        for (int i = 0; i < 8; ++i) *(s16x8*)(dst + i*8) = *(const s16x8*)(src + i*8);
    }
    __syncthreads();
    s16x8 aF[4];
    #pragma unroll
    for (int ks = 0; ks < 4; ++ks) aF[ks] = *(const s16x8*)(Abase + ks*32 + q4*8);
    #pragma unroll
    for (int nt = 0; nt < 8; ++nt)
        #pragma unroll
        for (int ks = 0; ks < 4; ++ks) {
            s16x8 bF = *(const s16x8*)(Wl + (nt*16+lm)*136 + ks*32 + q4*8);
            acc[nt] = mfma16(aF[ks], bF, acc[nt]);
        }
    int row = m0 + w*16 + q4*4;
    #pragma unroll
    for (int nt = 0; nt < 8; ++nt) {
        int ch = nt*16 + lm;
        float bs = ldf(bias, voff + ch, f);
        #pragma unroll
        for (int r = 0; r < 4; ++r)
            C[(size_t)(row+r)*HID + ch] = f2b(acc[nt][r] + bs);
    }
}

// ---------------------------------------------------------------------------
// Chained GEMM kernel: stage0 = attn-out@Wo + bias + resid + LayerNorm (same
// math as k_gemm EPI3), LN rows kept in-block; subsequent stages read the
// bf16 X from LDS (same rounding as the old global round-trip => identical
// numerics) with W re-staged per stage.
// MODE 0: stage0->fout, then 1 projection (W1,b1 -> O1)
// MODE 1: stage0->fout, then 3 projections (W1..3 -> O1..3)
// MODE 2: stage0 (no fout), mW1+BN/PReLU, mW2+BN/PReLU, dot(w3)+b3 -> outp
// All __syncthreads are top-level (wave-uniform).
// ---------------------------------------------------------------------------
template<int MODE>
__global__ __launch_bounds__(256) void k_chain(
    const u16* __restrict__ A, const u16* __restrict__ Wo,
    const u16* __restrict__ resid, u16* __restrict__ fout,
    const void* bo, const void* lgp, const void* lbp,
    const u16* __restrict__ W1, const void* b1, u16* __restrict__ O1,
    const u16* __restrict__ W2, const void* b2, u16* __restrict__ O2,
    const u16* __restrict__ W3, const void* b3, u16* __restrict__ O3,
    const void* g1, const void* bb1, const void* m1, const void* v1, const void* pa1,
    const void* g2, const void* bb2, const void* m2, const void* v2, const void* pa2,
    const void* w3p, const void* b3p, void* outp,
    const int* __restrict__ flags, int voff0, int voffP, int RB)
{
    __shared__ __align__(16) u16 Wl[128*136];
    __shared__ __align__(16) u16 Xb[64*136];
    int f = flags[0];
    int t = threadIdx.x, w = t>>6, lane = t&63, lm = lane&15, q4 = lane>>4;
    int m0 = blockIdx.x*64;
    int sr = t>>1, ss = (t&1)*64;
    int row = m0 + w*16 + q4*4;
    int lrow = w*16 + q4*4;

    // ---- stage 0: A @ Wo + bias + resid + LN ----
    {
        const u16* src = Wo + (size_t)sr*128 + ss;
        u16* dst = Wl + sr*136 + ss;
        #pragma unroll
        for (int i = 0; i < 8; ++i) *(s16x8*)(dst + i*8) = *(const s16x8*)(src + i*8);
    }
    __syncthreads();
    f32x4 acc[8];
    #pragma unroll
    for (int nt = 0; nt < 8; ++nt) acc[nt] = f32x4{0.f,0.f,0.f,0.f};
    {
        const u16* Abase = A + (size_t)(m0 + w*16 + lm)*128;
        s16x8 aF[4];
        #pragma unroll
        for (int ks = 0; ks < 4; ++ks) aF[ks] = *(const s16x8*)(Abase + ks*32 + q4*8);
        #pragma unroll
        for (int nt = 0; nt < 8; ++nt)
            #pragma unroll
            for (int ks = 0; ks < 4; ++ks) {
                s16x8 bF = *(const s16x8*)(Wl + (nt*16+lm)*136 + ks*32 + q4*8);
                acc[nt] = mfma16(aF[ks], bF, acc[nt]);
            }
    }
    float xs[8][4];
    #pragma unroll
    for (int nt = 0; nt < 8; ++nt) {
        int ch = nt*16 + lm;
        float bs = ldf(bo, voff0 + ch, f);
        #pragma unroll
        for (int r = 0; r < 4; ++r) {
            int rr = row + r;
            int rrow = RB ? (((rr>>12)<<8)|(rr&255)) : rr;
            xs[nt][r] = acc[nt][r] + bs + bfu(resid[(size_t)rrow*HID + ch]);
        }
    }
    #pragma unroll
    for (int r = 0; r < 4; ++r) {
        float sm = 0.f, sq = 0.f;
        #pragma unroll
        for (int nt = 0; nt < 8; ++nt) { sm += xs[nt][r]; sq += xs[nt][r]*xs[nt][r]; }
        #pragma unroll
        for (int d = 1; d <= 8; d <<= 1) { sm += __shfl_xor(sm, d); sq += __shfl_xor(sq, d); }
        float mean = sm * (1.f/128.f);
        float var  = sq * (1.f/128.f) - mean*mean;
        float rs   = rsqrtf(var + 1e-5f);
        #pragma unroll
        for (int nt = 0; nt < 8; ++nt) {
            int ch = nt*16 + lm;
            float g = ldf(lgp, voff0 + ch, f), bb = ldf(lbp, voff0 + ch, f);
            u16 v16 = f2b((xs[nt][r]-mean)*rs*g + bb);
            if (MODE < 2) fout[(size_t)(row+r)*HID + ch] = v16;
            Xb[(lrow+r)*136 + ch] = v16;
        }
    }
    __syncthreads();   // Xb complete; all Wl (stage0) reads done

    // A-frags of x0 from LDS; stage W1
    s16x8 aX[4];
    #pragma unroll
    for (int ks = 0; ks < 4; ++ks) aX[ks] = *(const s16x8*)(Xb + (w*16+lm)*136 + ks*32 + q4*8);
    {
        const u16* src = W1 + (size_t)sr*128 + ss;
        u16* dst = Wl + sr*136 + ss;
        #pragma unroll
        for (int i = 0; i < 8; ++i) *(s16x8*)(dst + i*8) = *(const s16x8*)(src + i*8);
    }
    __syncthreads();

    // ---- stage 1 ----
    #pragma unroll
    for (int nt = 0; nt < 8; ++nt) acc[nt] = f32x4{0.f,0.f,0.f,0.f};
    #pragma unroll
    for (int nt = 0; nt < 8; ++nt)
        #pragma unroll
        for (int ks = 0; ks < 4; ++ks) {
            s16x8 bF = *(const s16x8*)(Wl + (nt*16+lm)*136 + ks*32 + q4*8);
            acc[nt] = mfma16(aX[ks], bF, acc[nt]);
        }
    if (MODE < 2) {
        #pragma unroll
        for (int nt = 0; nt < 8; ++nt) {
            int ch = nt*16 + lm;
            float bs = ldf(b1, voffP + ch, f);
            #pragma unroll
            for (int r = 0; r < 4; ++r)
                O1[(size_t)(row+r)*HID + ch] = f2b(acc[nt][r] + bs);
        }
        if (MODE == 1) {
            // ---- stage 2 (K) ----
            __syncthreads();
            {
                const u16* src = W2 + (size_t)sr*128 + ss;
                u16* dst = Wl + sr*136 + ss;
                #pragma unroll
                for (int i = 0; i < 8; ++i) *(s16x8*)(dst + i*8) = *(const s16x8*)(src + i*8);
            }
            __syncthreads();
            #pragma unroll
            for (int nt = 0; nt < 8; ++nt) acc[nt] = f32x4{0.f,0.f,0.f,0.f};
            #pragma unroll
            for (int nt = 0; nt < 8; ++nt)
                #pragma unroll
                for (int ks = 0; ks < 4; ++ks) {
                    s16x8 bF = *(const s16x8*)(Wl + (nt*16+lm)*136 + ks*32 + q4*8);
                    acc[nt] = mfma16(aX[ks], bF, acc[nt]);
                }
            #pragma unroll
            for (int nt = 0; nt < 8; ++nt) {
                int ch = nt*16 + lm;
                float bs = ldf(b2, voffP + ch, f);
                #pragma unroll
                for (int r = 0; r < 4; ++r)
                    O2[(size_t)(row+r)*HID + ch] = f2b(acc[nt][r] + bs);
            }
            // ---- stage 3 (V) ----
            __syncthreads();
            {
                const u16* src = W3 + (size_t)sr*128 + ss;
                u16* dst = Wl + sr*136 + ss;
                #pragma unroll
                for (int i = 0; i < 8; ++i) *(s16x8*)(dst + i*8) = *(const s16x8*)(src + i*8);
            }
            __syncthreads();
            #pragma unroll
            for (int nt = 0; nt < 8; ++nt) acc[nt] = f32x4{0.f,0.f,0.f,0.f};
            #pragma unroll
            for (int nt = 0; nt < 8; ++nt)
                #pragma unroll
                for (int ks = 0; ks < 4; ++ks) {
                    s16x8 bF = *(const s16x8*)(Wl + (nt*16+lm)*136 + ks*32 + q4*8);
                    acc[nt] = mfma16(aX[ks], bF, acc[nt]);
                }
            #pragma unroll
            for (int nt = 0; nt < 8; ++nt) {
                int ch = nt*16 + lm;
                float bs = ldf(b3, voffP + ch, f);
                #pragma unroll
                for (int r = 0; r < 4; ++r)
                    O3[(size_t)(row+r)*HID + ch] = f2b(acc[nt][r] + bs);
            }
        }
    } else {
        // ---- MODE 2: mW1 + BN/PReLU -> Xb; mW2 + BN/PReLU; dot w3 ----
        u16 x1b[8][4];
        {
            float al1 = ldf(pa1, 0, f);
            #pragma unroll
            for (int nt = 0; nt < 8; ++nt) {
                int ch = nt*16 + lm;
                float bs = ldf(b1, ch, f);
                float g  = ldf(g1, ch, f), bb = ldf(bb1, ch, f);
                float mn = ldf(m1, ch, f), vv = ldf(v1, ch, f);
                float scl = g * rsqrtf(vv + 1e-5f);
                float sh  = bb - mn*scl;
                #pragma unroll
                for (int r = 0; r < 4; ++r) {
                    float x = acc[nt][r] + bs;
                    x = x*scl + sh;
                    x = (x >= 0.f) ? x : al1*x;
                    x1b[nt][r] = f2b(x);
                }
            }
        }
        __syncthreads();   // all aX reads of x0 + Wl(stage1) reads done
        #pragma unroll
        for (int nt = 0; nt < 8; ++nt)
            #pragma unroll
            for (int r = 0; r < 4; ++r)
                Xb[(lrow+r)*136 + nt*16 + lm] = x1b[nt][r];
        {
            const u16* src = W2 + (size_t)sr*128 + ss;
            u16* dst = Wl + sr*136 + ss;
            #pragma unroll
            for (int i = 0; i < 8; ++i) *(s16x8*)(dst + i*8) = *(const s16x8*)(src + i*8);
        }
        __syncthreads();
        #pragma unroll
        for (int ks = 0; ks < 4; ++ks) aX[ks] = *(const s16x8*)(Xb + (w*16+lm)*136 + ks*32 + q4*8);
        #pragma unroll
        for (int nt = 0; nt < 8; ++nt) acc[nt] = f32x4{0.f,0.f,0.f,0.f};
        #pragma unroll
        for (int nt = 0; nt < 8; ++nt)
            #pragma unroll
            for (int ks = 0; ks < 4; ++ks) {
                s16x8 bF = *(const s16x8*)(Wl + (nt*16+lm)*136 + ks*32 + q4*8);
                acc[nt] = mfma16(aX[ks], bF, acc[nt]);
            }
        float sum[4] = {0.f, 0.f, 0.f, 0.f};
        {
            float al2 = ldf(pa2, 0, f);
            #pragma unroll
            for (int nt = 0; nt < 8; ++nt) {
                int ch = nt*16 + lm;
                float bs = ldf(b2, ch, f);
                float g  = ldf(g2, ch, f), bb = ldf(bb2, ch, f);
                float mn = ldf(m2, ch, f), vv = ldf(v2, ch, f);
                float scl = g * rsqrtf(vv + 1e-5f);
                float sh  = bb - mn*scl;
                float w3v = ldf(w3p, ch, f);
                #pragma unroll
                for (int r = 0; r < 4; ++r) {
                    float x = acc[nt][r] + bs;
                    x = x*scl + sh;
                    x = (x >= 0.f) ? x : al2*x;
                    sum[r] += x * w3v;
                }
            }
        }
        #pragma unroll
        for (int r = 0; r < 4; ++r)
            #pragma unroll
            for (int d = 1; d <= 8; d <<= 1) sum[r] += __shfl_xor(sum[r], d);
        if (lm == 0) {
            float b3v = ldf(b3p, 0, f);
            #pragma unroll
            for (int r = 0; r < 4; ++r) {
                float rr = sum[r] + b3v;
                if (f) ((float*)outp)[row + r] = rr;
                else   ((u16*)outp)[row + r]  = f2b(rr);
            }
        }
    }
}

// ---------------------------------------------------------------------------
// Self-attention (unchanged from round 11 — passing).
// ---------------------------------------------------------------------------
template<int QTPB>
__global__ __launch_bounds__(256) void k_sattn(
    const u16* __restrict__ Q, const u16* __restrict__ K, const u16* __restrict__ V,
    u16* __restrict__ O, const void* __restrict__ center,
    const float* __restrict__ rsinv, const int* __restrict__ flags, int bdiv)
{
    __shared__ __align__(16) u16 Vt[32*264];
    __shared__ __align__(16) u16 P[4][16*40];
    __shared__ float cxl[256], cyl[256], czl[256], rsl[256];
    int s = blockIdx.x, h = blockIdx.y;
    int t = threadIdx.x, w = t>>6, lane = t&63, lm = lane&15, q4 = lane>>4;
    int f = flags[0];
    int b = s / bdiv;
    for (int idx = t; idx < 256*8; idx += 256) {
        int k = idx >> 3, d4 = idx & 7;
        ushort4 u = *(const ushort4*)(V + ((size_t)s*KQ + k)*HID + h*32 + d4*4);
        Vt[(d4*4+0)*264 + k] = u.x;
        Vt[(d4*4+1)*264 + k] = u.y;
        Vt[(d4*4+2)*264 + k] = u.z;
        Vt[(d4*4+3)*264 + k] = u.w;
    }
    {
        int j = (b << 8) + t;
        cxl[t] = ldf(center, j*3+0, f);
        cyl[t] = ldf(center, j*3+1, f);
        czl[t] = ldf(center, j*3+2, f);
        rsl[t] = rsinv[j];
    }
    __syncthreads();
    u16* Pw = P[w];
    const u16* Kbase = K + (size_t)s*KQ*HID + h*32;
    for (int qi = 0; qi < QTPB; ++qi) {
        int qt = blockIdx.z*QTPB + qi;
        int qrow0 = qt*64 + w*16;
        s16x8 aq = *(const s16x8*)(Q + ((size_t)s*KQ + qrow0 + lm)*HID + h*32 + q4*8);
        float qx[4], qy[4], qz[4];
        if (h < 2) {
            #pragma unroll
            for (int r = 0; r < 4; ++r) {
                int q = qrow0 + q4*4 + r;
                qx[r] = cxl[q]; qy[r] = cyl[q]; qz[r] = czl[q];
            }
        }
        float S[16][4];
        #pragma unroll
        for (int kt = 0; kt < 16; ++kt) {
            s16x8 bF = *(const s16x8*)(Kbase + (size_t)(kt*16 + lm)*HID + q4*8);
            f32x4 acc = f32x4{0.f,0.f,0.f,0.f};
            acc = mfma16(aq, bF, acc);
            int key = kt*16 + lm;
            float kx = 0.f, ky = 0.f, kz = 0.f, rs_ = 1.f;
            if (h < 2) { kx = cxl[key]; ky = cyl[key]; kz = czl[key]; rs_ = rsl[key]; }
            #pragma unroll
            for (int r = 0; r < 4; ++r) {
                float sc = acc[r]*SCALE_F;
                if (h < 2) {
                    float dx = qx[r]-kx, dy = qy[r]-ky, dz = qz[r]-kz;
                    float d  = sqrtf(dx*dx + dy*dy + dz*dz);
                    if (h == 0) sc += __builtin_amdgcn_rcpf(d + 0.01f) * rs_;
                    else        sc -= d;
                }
                S[kt][r] = sc;
            }
        }
        float linv[4];
        #pragma unroll
        for (int r = 0; r < 4; ++r) {
            float m = -3.0e38f;
            #pragma unroll
            for (int kt = 0; kt < 16; ++kt) m = fmaxf(m, S[kt][r]);
            #pragma unroll
            for (int d = 1; d <= 8; d <<= 1) m = fmaxf(m, __shfl_xor(m, d));
            float sum = 0.f;
            #pragma unroll
            for (int kt = 0; kt < 16; ++kt) { float p = __expf(S[kt][r]-m); S[kt][r] = p; sum += p; }
            #pragma unroll
            for (int d = 1; d <= 8; d <<= 1) sum += __shfl_xor(sum, d);
            linv[r] = __builtin_amdgcn_rcpf(sum);
        }
        f32x4 acc[2];
        acc[0] = f32x4{0.f,0.f,0.f,0.f};
        acc[1] = f32x4{0.f,0.f,0.f,0.f};
        #pragma unroll
        for (int ks = 0; ks < 8; ++ks) {
            #pragma unroll
            for (int kk = 0; kk < 2; ++kk)
                #pragma unroll
                for (int r = 0; r < 4; ++r)
                    Pw[(q4*4+r)*40 + kk*16 + lm] = f2b(S[ks*2+kk][r]);
            s16x8 ap = *(const s16x8*)(Pw + lm*40 + q4*8);
            #pragma unroll
            for (int nt = 0; nt < 2; ++nt) {
                s16x8 bv = *(const s16x8*)(Vt + (nt*16+lm)*264 + ks*32 + q4*8);
                acc[nt] = mfma16(ap, bv, acc[nt]);
            }
        }
        #pragma unroll
        for (int nt = 0; nt < 2; ++nt)
            #pragma unroll
            for (int r = 0; r < 4; ++r)
                O[((size_t)s*KQ + qrow0 + q4*4 + r)*HID + h*32 + nt*16 + lm] = f2b(acc[nt][r] * linv[r]);
    }
}

// ---------------------------------------------------------------------------
// Cross-attention (unchanged — passing).
// ---------------------------------------------------------------------------
__global__ __launch_bounds__(256) void k_xattn(
    const u16* __restrict__ Q, const u16* __restrict__ K, const u16* __restrict__ V,
    u16* __restrict__ O, const unsigned char* __restrict__ mask)
{
    __shared__ __align__(16) u16 Kl[64*40];
    __shared__ __align__(16) u16 Vt[32*72];
    __shared__ __align__(16) u16 P[4][16*72];
    __shared__ float madd[64];
    int s = blockIdx.x, h = blockIdx.y;
    int t = threadIdx.x, w = t>>6, lane = t&63, lm = lane&15, q4 = lane>>4;
    if (t < 64) {
        const u16* src = K + ((size_t)s*64 + t)*HID + h*32;
        u16* dst = Kl + t*40;
        #pragma unroll
        for (int i = 0; i < 4; ++i) *(s16x8*)(dst + i*8) = *(const s16x8*)(src + i*8);
        madd[t] = mask[s*64 + t] ? -1.0e9f : 0.f;
    }
    for (int idx = t; idx < 64*8; idx += 256) {
        int k = idx >> 3, d4 = idx & 7;
        ushort4 u = *(const ushort4*)(V + ((size_t)s*64 + k)*HID + h*32 + d4*4);
        Vt[(d4*4+0)*72 + k] = u.x;
        Vt[(d4*4+1)*72 + k] = u.y;
        Vt[(d4*4+2)*72 + k] = u.z;
        Vt[(d4*4+3)*72 + k] = u.w;
    }
    __syncthreads();
    u16* Pw = P[w];
    for (int qt = 0; qt < 4; ++qt) {
        int qrow0 = qt*64 + w*16;
        s16x8 aq = *(const s16x8*)(Q + ((size_t)s*KQ + qrow0 + lm)*HID + h*32 + q4*8);
        float S[4][4];
        #pragma unroll
        for (int kt = 0; kt < 4; ++kt) {
            s16x8 bF = *(const s16x8*)(Kl + (kt*16+lm)*40 + q4*8);
            f32x4 acc = f32x4{0.f,0.f,0.f,0.f};
            acc = mfma16(aq, bF, acc);
            float ma = madd[kt*16 + lm];
            #pragma unroll
            for (int r = 0; r < 4; ++r) S[kt][r] = acc[r]*SCALE_F + ma;
        }
        float linv[4];
        #pragma unroll
        for (int r = 0; r < 4; ++r) {
            float m = -3.0e38f;
            #pragma unroll
            for (int kt = 0; kt < 4; ++kt) m = fmaxf(m, S[kt][r]);
            #pragma unroll
            for (int d = 1; d <= 8; d <<= 1) m = fmaxf(m, __shfl_xor(m, d));
            float sum = 0.f;
            #pragma unroll
            for (int kt = 0; kt < 4; ++kt) { float p = __expf(S[kt][r]-m); S[kt][r] = p; sum += p; }
            #pragma unroll
            for (int d = 1; d <= 8; d <<= 1) sum += __shfl_xor(sum, d);
            linv[r] = __builtin_amdgcn_rcpf(sum);
        }
        #pragma unroll
        for (int kt = 0; kt < 4; ++kt)
            #pragma unroll
            for (int r = 0; r < 4; ++r)
                Pw[(q4*4+r)*72 + kt*16 + lm] = f2b(S[kt][r]);
        #pragma unroll
        for (int nt = 0; nt < 2; ++nt) {
            f32x4 acc = f32x4{0.f,0.f,0.f,0.f};
            #pragma unroll
            for (int ks = 0; ks < 2; ++ks) {
                s16x8 ap = *(const s16x8*)(Pw + lm*72 + ks*32 + q4*8);
                s16x8 bv = *(const s16x8*)(Vt + (nt*16+lm)*72 + ks*32 + q4*8);
                acc = mfma16(ap, bv, acc);
            }
            #pragma unroll
            for (int r = 0; r < 4; ++r)
                O[((size_t)s*KQ + qrow0 + q4*4 + r)*HID + h*32 + nt*16 + lm] = f2b(acc[r] * linv[r]);
        }
    }
}

// ---------------------------------------------------------------------------
extern "C" void kernel_launch(void* const* d_in, const int* in_sizes, int n_in,
                              void* d_out, int out_size, void* d_ws, size_t ws_size,
                              hipStream_t stream)
{
    (void)n_in;
    if (ws_size < (size_t)NEEDF * 4) {
        fprintf(stderr, "kernel_launch: ws too small: have %zu need %zu\n",
                ws_size, (size_t)NEEDF * 4);
        hipMemsetAsync(d_out, 0, (size_t)out_size * 2, stream);
        return;
    }
    float* F = (float*)d_ws;
    u16*   U = (u16*)d_ws;
    int* flags = (int*)d_ws;
    u16* WB     = U + (size_t)OFF_WB*2;
    u16* langb  = U + (size_t)OFF_LANGB*2;
    u16* detrb  = U + (size_t)OFF_KB*2;
    u16* featsb = U + (size_t)OFF_FEATSB*2;
    u16* x2b    = U + (size_t)OFF_FAB*2;
    u16* fAb    = U + (size_t)OFF_FAB*2;
    u16* x1b    = U + (size_t)OFF_VB*2;
    u16* Qb     = U + (size_t)OFF_QB*2;
    u16* Kb     = U + (size_t)OFF_KB*2;
    u16* Vb     = U + (size_t)OFF_VB*2;
    float* rsinv = F + OFF_ROWS;
    unsigned char* mask8 = (unsigned char*)(F + OFF_MASK);

    k_detect<<<1, 256, 0, stream>>>((const unsigned*)d_in[8],
                                    (const unsigned*)d_in[48], flags);
    k_mask_canon<<<64, 256, 0, stream>>>((const unsigned char*)d_in[48], flags, mask8);

    CvTab ct;
    {
        const int idx[14] = {3,18,20,21,22,23,30,31,32,33,40,43,1,2};
        const unsigned long long dst[14] = {
            (unsigned long long)OFF_WB*2 + WB_FCW1, (unsigned long long)OFF_WB*2 + WB_FCW2,
            (unsigned long long)OFF_WB*2 + WB_SAWQ, (unsigned long long)OFF_WB*2 + WB_SAWK,
            (unsigned long long)OFF_WB*2 + WB_SAWV, (unsigned long long)OFF_WB*2 + WB_SAWO,
            (unsigned long long)OFF_WB*2 + WB_CAWQ, (unsigned long long)OFF_WB*2 + WB_CAWK,
            (unsigned long long)OFF_WB*2 + WB_CAWV, (unsigned long long)OFF_WB*2 + WB_CAWO,
            (unsigned long long)OFF_WB*2 + WB_MW1,  (unsigned long long)OFF_WB*2 + WB_MW2,
            (unsigned long long)OFF_KB*2,           (unsigned long long)OFF_LANGB*2 };
        const int bs[15] = {0,144,160,192,224,256,288,320,352,384,416,432,448,5056,7104};
        for (int e = 0; e < 14; ++e) { ct.src[e] = d_in[idx[e]]; ct.dst[e] = dst[e]; }
        for (int e = 0; e < 15; ++e) ct.bstart[e] = bs[e];
    }
    k_convAll<<<7104, 256, 0, stream>>>(ct, U, flags);

    k_rowsum<<<4096, 256, 0, stream>>>(d_in[0], rsinv, flags);

    const void* N0 = nullptr;
    const u16*  NU = nullptr;

    // features_concat
    k_gemm<1,false,false><<<64, 256, 0, stream>>>(detrb, WB+WB_FCW1, x1b, 1152,
        d_in[4], d_in[5], d_in[6], d_in[7], d_in[8], d_in[17], N0, N0, nullptr, flags, 0);
    k_gemm<0,false,false><<<64, 256, 0, stream>>>(x1b, WB+WB_FCW2, x2b, 128,
        d_in[19], N0,N0,N0,N0,N0, N0, N0, nullptr, flags, 0);

    // sa0
    k_gemmN<false><<<dim3(64,3), 256, 0, stream>>>(x2b,
        WB+WB_SAWQ, WB+WB_SAWK, WB+WB_SAWV, Qb, Kb, Vb,
        d_in[24], d_in[25], d_in[26], flags, 0);
    k_sattn<1><<<dim3(16,4,4), 256, 0, stream>>>(Qb, Kb, Vb, Qb, d_in[0], rsinv, flags, 1);
    k_gemm<3,false,false><<<64, 256, 0, stream>>>(Qb, WB+WB_SAWO, featsb, 128,
        d_in[27], N0,N0,N0,N0,N0, d_in[29], d_in[28], x2b, flags, 0);

    // ca0
    k_gemm<0,true,false><<<1024, 256, 0, stream>>>(featsb, WB+WB_CAWQ, Qb, 128,
        d_in[34], N0,N0,N0,N0,N0, N0, N0, nullptr, flags, 0);
    k_gemmN<false><<<dim3(256,2), 256, 0, stream>>>(langb,
        WB+WB_CAWK, WB+WB_CAWV, nullptr, Kb, Vb, nullptr,
        d_in[35], d_in[36], nullptr, flags, 0);
    k_xattn<<<dim3(256,4), 256, 0, stream>>>(Qb, Kb, Vb, Qb, mask8);

    // chain4: ca0 O-proj+resid(featsb,BCAST)+LN -> fAb, then sa1 Q/K/V projections
    k_chain<1><<<1024, 256, 0, stream>>>(
        Qb, WB+WB_CAWO, featsb, fAb,
        d_in[37], d_in[39], d_in[38],
        WB+WB_SAWQ+16384, d_in[24], Qb,
        WB+WB_SAWK+16384, d_in[25], Kb,
        WB+WB_SAWV+16384, d_in[26], Vb,
        N0,N0,N0,N0,N0, N0,N0,N0,N0,N0, N0, N0, nullptr,
        flags, 0, 128, 1);

    // sa1
    k_sattn<4><<<dim3(256,4,1), 256, 0, stream>>>(Qb, Kb, Vb, Qb, d_in[0], rsinv, flags, 16);

    // chain2: sa1 O-proj+resid(fAb)+LN -> fAb, then ca1 Q projection
    k_chain<0><<<1024, 256, 0, stream>>>(
        Qb, WB+WB_SAWO+16384, fAb, fAb,
        d_in[27], d_in[29], d_in[28],
        WB+WB_CAWQ+16384, d_in[34], Qb,
        NU, N0, nullptr, NU, N0, nullptr,
        N0,N0,N0,N0,N0, N0,N0,N0,N0,N0, N0, N0, nullptr,
        flags, 128, 128, 0);

    // ca1
    k_gemmN<false><<<dim3(256,2), 256, 0, stream>>>(langb,
        WB+WB_CAWK+16384, WB+WB_CAWV+16384, nullptr, Kb, Vb, nullptr,
        d_in[35], d_in[36], nullptr, flags, 128);
    k_xattn<<<dim3(256,4), 256, 0, stream>>>(Qb, Kb, Vb, Qb, mask8);

    // tail: ca1 O-proj+resid(fAb)+LN (no global write), mW1+BN/PReLU,
    // mW2+BN/PReLU, dot(w3)+b3 -> d_out
    k_chain<2><<<1024, 256, 0, stream>>>(
        Qb, WB+WB_CAWO+16384, fAb, nullptr,
        d_in[37], d_in[39], d_in[38],
        WB+WB_MW1, d_in[41], nullptr,
        WB+WB_MW2, d_in[44], nullptr,
        NU, N0, nullptr,
        d_in[9], d_in[10], d_in[11], d_in[12], d_in[42],
        d_in[13], d_in[14], d_in[15], d_in[16], d_in[45],
        d_in[46], d_in[47], d_out,
        flags, 128, 0, 0);
}

// Round 13
// 488.721 us; speedup vs baseline: 1.4276x; 1.4276x over previous
//
#include <hip/hip_runtime.h>
#include <hip/hip_bf16.h>
#include <cstdio>

#define KQ   256
#define HID  128
typedef unsigned short u16;
#define SCALE_F 0.1767766952966369f  // 1/sqrt(32)

typedef __bf16 bf16x8 __attribute__((ext_vector_type(8)));
typedef short  s16x8  __attribute__((ext_vector_type(8)));
typedef float  f32x4  __attribute__((ext_vector_type(4)));

static __device__ __forceinline__ float bfu(u16 u) {
    return __uint_as_float(((unsigned)u) << 16);
}
static __device__ __forceinline__ u16 f2b(float f) {
    unsigned u = __float_as_uint(f);
    return (u16)((u + 0x7FFFu + ((u >> 16) & 1u)) >> 16);  // RNE
}
static __device__ __forceinline__ float ldf(const void* p, int i, int f) {
    return f ? ((const float*)p)[i] : bfu(((const u16*)p)[i]);
}
static __device__ __forceinline__ f32x4 mfma16(s16x8 a, s16x8 b, f32x4 c) {
    return __builtin_amdgcn_mfma_f32_16x16x32_bf16(
        __builtin_bit_cast(bf16x8, a), __builtin_bit_cast(bf16x8, b), c, 0, 0, 0);
}

// ---------------------------------------------------------------------------
// Workspace layout (f32 units) — unchanged from rounds 5/7/10/11 (passing).
// ---------------------------------------------------------------------------
#define OFF_WB     8256
#define OFF_LANGB  237632
#define OFF_ROWS   3383360
#define OFF_FEATSB 3387456
#define OFF_FAB    3649600
#define OFF_QB     7843904
#define OFF_KB     12038208
#define OFF_VB     16232512
#define OFF_MASK   20426816
#define NEEDF      20430912

#define WB_FCW1 0
#define WB_FCW2 147456
#define WB_SAWQ 163840
#define WB_SAWK 196608
#define WB_SAWV 229376
#define WB_SAWO 262144
#define WB_CAWQ 294912
#define WB_CAWK 327680
#define WB_CAWV 360448
#define WB_CAWO 393216
#define WB_MW1  425984
#define WB_MW2  442368

// ---------------------------------------------------------------------------
__global__ __launch_bounds__(256) void k_detect(
    const unsigned* __restrict__ onesw, const unsigned* __restrict__ maskw,
    int* __restrict__ flags)
{
    __shared__ int fb;
    if (threadIdx.x == 0) fb = 0;
    __syncthreads();
    int any = 0;
    for (int i = threadIdx.x; i < 4096; i += 256) any |= (maskw[i] > 1u) ? 1 : 0;
    if (any) atomicOr(&fb, 1);
    __syncthreads();
    if (threadIdx.x == 0) {
        flags[0] = (onesw[0] == 0x3F800000u) ? 1 : 0;
        flags[1] = fb;
    }
}

__global__ __launch_bounds__(256) void k_mask_canon(
    const unsigned char* __restrict__ raw, const int* __restrict__ flags,
    unsigned char* __restrict__ mask8)
{
    int i = blockIdx.x*256 + threadIdx.x;
    if (flags[1]) mask8[i] = raw[i] ? 1 : 0;
    else          mask8[i] = (((const unsigned int*)raw)[i] != 0u) ? 1 : 0;
}

// All bf16 conversions in ONE launch (verified passing rounds 10/11/12).
struct CvTab {
    const void* src[14];
    unsigned long long dst[14];   // u16 offset from U
    int bstart[15];
};
__global__ __launch_bounds__(256) void k_convAll(
    CvTab t, u16* __restrict__ U, const int* __restrict__ flags)
{
    int b = blockIdx.x;
    int e = 0;
    while (e < 13 && b >= t.bstart[e+1]) ++e;
    long long local = (long long)(b - t.bstart[e])*1024 + threadIdx.x*4;
    u16* dst = U + t.dst[e] + local;
    if (flags[0]) {
        float4 v = *((const float4*)t.src[e] + (local >> 2));
        ushort4 o; o.x = f2b(v.x); o.y = f2b(v.y); o.z = f2b(v.z); o.w = f2b(v.w);
        *(ushort4*)dst = o;
    } else {
        *(ushort4*)dst = *((const ushort4*)t.src[e] + (local >> 2));
    }
}

// ---------------------------------------------------------------------------
// Inverse row sums of 1/(d+0.01) (verified passing).
// ---------------------------------------------------------------------------
__global__ __launch_bounds__(256) void k_rowsum(
    const void* __restrict__ center, float* __restrict__ rsinv,
    const int* __restrict__ flags)
{
    int f  = flags[0];
    int bi = blockIdx.x, b = bi >> 8, j = threadIdx.x;
    float cx = ldf(center, bi*3+0, f), cy = ldf(center, bi*3+1, f), cz = ldf(center, bi*3+2, f);
    int pj = (b << 8) + j;
    float px = ldf(center, pj*3+0, f), py = ldf(center, pj*3+1, f), pz = ldf(center, pj*3+2, f);
    float dx = px-cx, dy = py-cy, dz = pz-cz;
    float d  = sqrtf(dx*dx + dy*dy + dz*dz);
    float w  = 1.f/(d + 0.01f);
    float sw = w;
    #pragma unroll
    for (int m = 32; m >= 1; m >>= 1) sw += __shfl_xor(sw, m);
    __shared__ float red[4];
    if ((j & 63) == 0) red[j >> 6] = sw;
    __syncthreads();
    if (j == 0) rsinv[bi] = 1.f / (red[0] + red[1] + red[2] + red[3]);
}

// ---------------------------------------------------------------------------
// MFMA GEMM (unchanged; EPI 0/1/3 still used).
// ---------------------------------------------------------------------------
template<int EPI, bool ABCAST, bool RBCAST>
__global__ __launch_bounds__(256) void k_gemm(
    const u16* __restrict__ A, const u16* __restrict__ W, u16* __restrict__ C,
    int Kd, const void* __restrict__ bias,
    const void* __restrict__ bng, const void* __restrict__ bnb,
    const void* __restrict__ bnm, const void* __restrict__ bnv,
    const void* __restrict__ pa,
    const void* __restrict__ lg, const void* __restrict__ lb,
    const u16* __restrict__ resid, const int* __restrict__ flags, int voff)
{
    __shared__ __align__(16) u16 Wl[128*136];
    int f = flags[0];
    int t = threadIdx.x, w = t>>6, lane = t&63, lm = lane&15, q4 = lane>>4;
    int m0 = blockIdx.x*64;
    int arow = m0 + w*16 + lm;
    int grow = ABCAST ? (((arow>>12)<<8)|(arow&255)) : arow;
    const u16* Abase = A + (size_t)grow*Kd;
    f32x4 acc[8];
    #pragma unroll
    for (int nt = 0; nt < 8; ++nt) acc[nt] = f32x4{0.f,0.f,0.f,0.f};
    int sr = t>>1, ss = (t&1)*64;
    for (int k0 = 0; k0 < Kd; k0 += 128) {
        const u16* src = W + (size_t)sr*Kd + k0 + ss;
        u16* dst = Wl + sr*136 + ss;
        #pragma unroll
        for (int i = 0; i < 8; ++i) *(s16x8*)(dst + i*8) = *(const s16x8*)(src + i*8);
        __syncthreads();
        s16x8 aF[4];
        #pragma unroll
        for (int ks = 0; ks < 4; ++ks) aF[ks] = *(const s16x8*)(Abase + k0 + ks*32 + q4*8);
        #pragma unroll
        for (int nt = 0; nt < 8; ++nt)
            #pragma unroll
            for (int ks = 0; ks < 4; ++ks) {
                s16x8 bF = *(const s16x8*)(Wl + (nt*16+lm)*136 + ks*32 + q4*8);
                acc[nt] = mfma16(aF[ks], bF, acc[nt]);
            }
        __syncthreads();
    }
    int row = m0 + w*16 + q4*4;
    if (EPI == 3) {
        float xs[8][4];
        #pragma unroll
        for (int nt = 0; nt < 8; ++nt) {
            int ch = nt*16 + lm;
            float bs = ldf(bias, voff + ch, f);
            #pragma unroll
            for (int r = 0; r < 4; ++r) {
                int rr = row + r;
                int rrow = RBCAST ? (((rr>>12)<<8)|(rr&255)) : rr;
                xs[nt][r] = acc[nt][r] + bs + bfu(resid[(size_t)rrow*HID + ch]);
            }
        }
        #pragma unroll
        for (int r = 0; r < 4; ++r) {
            float sm = 0.f, sq = 0.f;
            #pragma unroll
            for (int nt = 0; nt < 8; ++nt) { sm += xs[nt][r]; sq += xs[nt][r]*xs[nt][r]; }
            #pragma unroll
            for (int d = 1; d <= 8; d <<= 1) { sm += __shfl_xor(sm, d); sq += __shfl_xor(sq, d); }
            float mean = sm * (1.f/128.f);
            float var  = sq * (1.f/128.f) - mean*mean;
            float rs   = rsqrtf(var + 1e-5f);
            #pragma unroll
            for (int nt = 0; nt < 8; ++nt) {
                int ch = nt*16 + lm;
                float g = ldf(lg, voff + ch, f), bb = ldf(lb, voff + ch, f);
                C[(size_t)(row+r)*HID + ch] = f2b((xs[nt][r]-mean)*rs*g + bb);
            }
        }
    } else {
        #pragma unroll
        for (int nt = 0; nt < 8; ++nt) {
            int ch = nt*16 + lm;
            float bs = ldf(bias, voff + ch, f);
            float scl = 1.f, sh = 0.f, al = 0.f;
            if (EPI >= 1) {
                float g  = ldf(bng, ch, f), bb = ldf(bnb, ch, f);
                float mn = ldf(bnm, ch, f), vv = ldf(bnv, ch, f);
                scl = g * rsqrtf(vv + 1e-5f);
                sh  = bb - mn*scl;
                al  = ldf(pa, ch, f);
            }
            #pragma unroll
            for (int r = 0; r < 4; ++r) {
                float x = acc[nt][r] + bs;
                if (EPI >= 1) { x = x*scl + sh; x = (x >= 0.f) ? x : al*x; }
                C[(size_t)(row+r)*HID + ch] = f2b(x);
            }
        }
    }
}

// ---------------------------------------------------------------------------
// Triple-output GEMM (unchanged — passing).
// ---------------------------------------------------------------------------
template<bool ABCAST>
__global__ __launch_bounds__(256) void k_gemmN(
    const u16* __restrict__ A,
    const u16* __restrict__ W0, const u16* __restrict__ W1, const u16* __restrict__ W2,
    u16* __restrict__ C0, u16* __restrict__ C1, u16* __restrict__ C2,
    const void* __restrict__ b0, const void* __restrict__ b1, const void* __restrict__ b2,
    const int* __restrict__ flags, int voff)
{
    __shared__ __align__(16) u16 Wl[128*136];
    int y = blockIdx.y;
    const u16* W = (y == 0) ? W0 : (y == 1) ? W1 : W2;
    u16* C = (y == 0) ? C0 : (y == 1) ? C1 : C2;
    const void* bias = (y == 0) ? b0 : (y == 1) ? b1 : b2;
    int f = flags[0];
    int t = threadIdx.x, w = t>>6, lane = t&63, lm = lane&15, q4 = lane>>4;
    int m0 = blockIdx.x*64;
    int arow = m0 + w*16 + lm;
    int grow = ABCAST ? (((arow>>12)<<8)|(arow&255)) : arow;
    const u16* Abase = A + (size_t)grow*128;
    f32x4 acc[8];
    #pragma unroll
    for (int nt = 0; nt < 8; ++nt) acc[nt] = f32x4{0.f,0.f,0.f,0.f};
    int sr = t>>1, ss = (t&1)*64;
    {
        const u16* src = W + (size_t)sr*128 + ss;
        u16* dst = Wl + sr*136 + ss;
        #pragma unroll
        for (int i = 0; i < 8; ++i) *(s16x8*)(dst + i*8) = *(const s16x8*)(src + i*8);
    }
    __syncthreads();
    s16x8 aF[4];
    #pragma unroll
    for (int ks = 0; ks < 4; ++ks) aF[ks] = *(const s16x8*)(Abase + ks*32 + q4*8);
    #pragma unroll
    for (int nt = 0; nt < 8; ++nt)
        #pragma unroll
        for (int ks = 0; ks < 4; ++ks) {
            s16x8 bF = *(const s16x8*)(Wl + (nt*16+lm)*136 + ks*32 + q4*8);
            acc[nt] = mfma16(aF[ks], bF, acc[nt]);
        }
    int row = m0 + w*16 + q4*4;
    #pragma unroll
    for (int nt = 0; nt < 8; ++nt) {
        int ch = nt*16 + lm;
        float bs = ldf(bias, voff + ch, f);
        #pragma unroll
        for (int r = 0; r < 4; ++r)
            C[(size_t)(row+r)*HID + ch] = f2b(acc[nt][r] + bs);
    }
}

// ---------------------------------------------------------------------------
// Chained GEMM kernel (unchanged from round 12 — passed with absmax 3.9e-3;
// the round-12 dur regression is attributed to a 1.5x-slower container:
// byte-identical k_sattn ran 75->114us with identical counters).
// MODE 0: stage0->fout, then 1 projection; MODE 1: stage0->fout + Q/K/V;
// MODE 2: stage0, mW1+BN/PReLU, mW2+BN/PReLU, dot(w3)+b3 -> outp.
// ---------------------------------------------------------------------------
template<int MODE>
__global__ __launch_bounds__(256) void k_chain(
    const u16* __restrict__ A, const u16* __restrict__ Wo,
    const u16* __restrict__ resid, u16* __restrict__ fout,
    const void* bo, const void* lgp, const void* lbp,
    const u16* __restrict__ W1, const void* b1, u16* __restrict__ O1,
    const u16* __restrict__ W2, const void* b2, u16* __restrict__ O2,
    const u16* __restrict__ W3, const void* b3, u16* __restrict__ O3,
    const void* g1, const void* bb1, const void* m1, const void* v1, const void* pa1,
    const void* g2, const void* bb2, const void* m2, const void* v2, const void* pa2,
    const void* w3p, const void* b3p, void* outp,
    const int* __restrict__ flags, int voff0, int voffP, int RB)
{
    __shared__ __align__(16) u16 Wl[128*136];
    __shared__ __align__(16) u16 Xb[64*136];
    int f = flags[0];
    int t = threadIdx.x, w = t>>6, lane = t&63, lm = lane&15, q4 = lane>>4;
    int m0 = blockIdx.x*64;
    int sr = t>>1, ss = (t&1)*64;
    int row = m0 + w*16 + q4*4;
    int lrow = w*16 + q4*4;

    // ---- stage 0: A @ Wo + bias + resid + LN ----
    {
        const u16* src = Wo + (size_t)sr*128 + ss;
        u16* dst = Wl + sr*136 + ss;
        #pragma unroll
        for (int i = 0; i < 8; ++i) *(s16x8*)(dst + i*8) = *(const s16x8*)(src + i*8);
    }
    __syncthreads();
    f32x4 acc[8];
    #pragma unroll
    for (int nt = 0; nt < 8; ++nt) acc[nt] = f32x4{0.f,0.f,0.f,0.f};
    {
        const u16* Abase = A + (size_t)(m0 + w*16 + lm)*128;
        s16x8 aF[4];
        #pragma unroll
        for (int ks = 0; ks < 4; ++ks) aF[ks] = *(const s16x8*)(Abase + ks*32 + q4*8);
        #pragma unroll
        for (int nt = 0; nt < 8; ++nt)
            #pragma unroll
            for (int ks = 0; ks < 4; ++ks) {
                s16x8 bF = *(const s16x8*)(Wl + (nt*16+lm)*136 + ks*32 + q4*8);
                acc[nt] = mfma16(aF[ks], bF, acc[nt]);
            }
    }
    float xs[8][4];
    #pragma unroll
    for (int nt = 0; nt < 8; ++nt) {
        int ch = nt*16 + lm;
        float bs = ldf(bo, voff0 + ch, f);
        #pragma unroll
        for (int r = 0; r < 4; ++r) {
            int rr = row + r;
            int rrow = RB ? (((rr>>12)<<8)|(rr&255)) : rr;
            xs[nt][r] = acc[nt][r] + bs + bfu(resid[(size_t)rrow*HID + ch]);
        }
    }
    #pragma unroll
    for (int r = 0; r < 4; ++r) {
        float sm = 0.f, sq = 0.f;
        #pragma unroll
        for (int nt = 0; nt < 8; ++nt) { sm += xs[nt][r]; sq += xs[nt][r]*xs[nt][r]; }
        #pragma unroll
        for (int d = 1; d <= 8; d <<= 1) { sm += __shfl_xor(sm, d); sq += __shfl_xor(sq, d); }
        float mean = sm * (1.f/128.f);
        float var  = sq * (1.f/128.f) - mean*mean;
        float rs   = rsqrtf(var + 1e-5f);
        #pragma unroll
        for (int nt = 0; nt < 8; ++nt) {
            int ch = nt*16 + lm;
            float g = ldf(lgp, voff0 + ch, f), bb = ldf(lbp, voff0 + ch, f);
            u16 v16 = f2b((xs[nt][r]-mean)*rs*g + bb);
            if (MODE < 2) fout[(size_t)(row+r)*HID + ch] = v16;
            Xb[(lrow+r)*136 + ch] = v16;
        }
    }
    __syncthreads();   // Xb complete; all Wl (stage0) reads done

    // A-frags of x0 from LDS; stage W1
    s16x8 aX[4];
    #pragma unroll
    for (int ks = 0; ks < 4; ++ks) aX[ks] = *(const s16x8*)(Xb + (w*16+lm)*136 + ks*32 + q4*8);
    {
        const u16* src = W1 + (size_t)sr*128 + ss;
        u16* dst = Wl + sr*136 + ss;
        #pragma unroll
        for (int i = 0; i < 8; ++i) *(s16x8*)(dst + i*8) = *(const s16x8*)(src + i*8);
    }
    __syncthreads();

    // ---- stage 1 ----
    #pragma unroll
    for (int nt = 0; nt < 8; ++nt) acc[nt] = f32x4{0.f,0.f,0.f,0.f};
    #pragma unroll
    for (int nt = 0; nt < 8; ++nt)
        #pragma unroll
        for (int ks = 0; ks < 4; ++ks) {
            s16x8 bF = *(const s16x8*)(Wl + (nt*16+lm)*136 + ks*32 + q4*8);
            acc[nt] = mfma16(aX[ks], bF, acc[nt]);
        }
    if (MODE < 2) {
        #pragma unroll
        for (int nt = 0; nt < 8; ++nt) {
            int ch = nt*16 + lm;
            float bs = ldf(b1, voffP + ch, f);
            #pragma unroll
            for (int r = 0; r < 4; ++r)
                O1[(size_t)(row+r)*HID + ch] = f2b(acc[nt][r] + bs);
        }
        if (MODE == 1) {
            // ---- stage 2 (K) ----
            __syncthreads();
            {
                const u16* src = W2 + (size_t)sr*128 + ss;
                u16* dst = Wl + sr*136 + ss;
                #pragma unroll
                for (int i = 0; i < 8; ++i) *(s16x8*)(dst + i*8) = *(const s16x8*)(src + i*8);
            }
            __syncthreads();
            #pragma unroll
            for (int nt = 0; nt < 8; ++nt) acc[nt] = f32x4{0.f,0.f,0.f,0.f};
            #pragma unroll
            for (int nt = 0; nt < 8; ++nt)
                #pragma unroll
                for (int ks = 0; ks < 4; ++ks) {
                    s16x8 bF = *(const s16x8*)(Wl + (nt*16+lm)*136 + ks*32 + q4*8);
                    acc[nt] = mfma16(aX[ks], bF, acc[nt]);
                }
            #pragma unroll
            for (int nt = 0; nt < 8; ++nt) {
                int ch = nt*16 + lm;
                float bs = ldf(b2, voffP + ch, f);
                #pragma unroll
                for (int r = 0; r < 4; ++r)
                    O2[(size_t)(row+r)*HID + ch] = f2b(acc[nt][r] + bs);
            }
            // ---- stage 3 (V) ----
            __syncthreads();
            {
                const u16* src = W3 + (size_t)sr*128 + ss;
                u16* dst = Wl + sr*136 + ss;
                #pragma unroll
                for (int i = 0; i < 8; ++i) *(s16x8*)(dst + i*8) = *(const s16x8*)(src + i*8);
            }
            __syncthreads();
            #pragma unroll
            for (int nt = 0; nt < 8; ++nt) acc[nt] = f32x4{0.f,0.f,0.f,0.f};
            #pragma unroll
            for (int nt = 0; nt < 8; ++nt)
                #pragma unroll
                for (int ks = 0; ks < 4; ++ks) {
                    s16x8 bF = *(const s16x8*)(Wl + (nt*16+lm)*136 + ks*32 + q4*8);
                    acc[nt] = mfma16(aX[ks], bF, acc[nt]);
                }
            #pragma unroll
            for (int nt = 0; nt < 8; ++nt) {
                int ch = nt*16 + lm;
                float bs = ldf(b3, voffP + ch, f);
                #pragma unroll
                for (int r = 0; r < 4; ++r)
                    O3[(size_t)(row+r)*HID + ch] = f2b(acc[nt][r] + bs);
            }
        }
    } else {
        // ---- MODE 2: mW1 + BN/PReLU -> Xb; mW2 + BN/PReLU; dot w3 ----
        u16 x1b[8][4];
        {
            float al1 = ldf(pa1, 0, f);
            #pragma unroll
            for (int nt = 0; nt < 8; ++nt) {
                int ch = nt*16 + lm;
                float bs = ldf(b1, ch, f);
                float g  = ldf(g1, ch, f), bb = ldf(bb1, ch, f);
                float mn = ldf(m1, ch, f), vv = ldf(v1, ch, f);
                float scl = g * rsqrtf(vv + 1e-5f);
                float sh  = bb - mn*scl;
                #pragma unroll
                for (int r = 0; r < 4; ++r) {
                    float x = acc[nt][r] + bs;
                    x = x*scl + sh;
                    x = (x >= 0.f) ? x : al1*x;
                    x1b[nt][r] = f2b(x);
                }
            }
        }
        __syncthreads();   // all aX reads of x0 + Wl(stage1) reads done
        #pragma unroll
        for (int nt = 0; nt < 8; ++nt)
            #pragma unroll
            for (int r = 0; r < 4; ++r)
                Xb[(lrow+r)*136 + nt*16 + lm] = x1b[nt][r];
        {
            const u16* src = W2 + (size_t)sr*128 + ss;
            u16* dst = Wl + sr*136 + ss;
            #pragma unroll
            for (int i = 0; i < 8; ++i) *(s16x8*)(dst + i*8) = *(const s16x8*)(src + i*8);
        }
        __syncthreads();
        #pragma unroll
        for (int ks = 0; ks < 4; ++ks) aX[ks] = *(const s16x8*)(Xb + (w*16+lm)*136 + ks*32 + q4*8);
        #pragma unroll
        for (int nt = 0; nt < 8; ++nt) acc[nt] = f32x4{0.f,0.f,0.f,0.f};
        #pragma unroll
        for (int nt = 0; nt < 8; ++nt)
            #pragma unroll
            for (int ks = 0; ks < 4; ++ks) {
                s16x8 bF = *(const s16x8*)(Wl + (nt*16+lm)*136 + ks*32 + q4*8);
                acc[nt] = mfma16(aX[ks], bF, acc[nt]);
            }
        float sum[4] = {0.f, 0.f, 0.f, 0.f};
        {
            float al2 = ldf(pa2, 0, f);
            #pragma unroll
            for (int nt = 0; nt < 8; ++nt) {
                int ch = nt*16 + lm;
                float bs = ldf(b2, ch, f);
                float g  = ldf(g2, ch, f), bb = ldf(bb2, ch, f);
                float mn = ldf(m2, ch, f), vv = ldf(v2, ch, f);
                float scl = g * rsqrtf(vv + 1e-5f);
                float sh  = bb - mn*scl;
                float w3v = ldf(w3p, ch, f);
                #pragma unroll
                for (int r = 0; r < 4; ++r) {
                    float x = acc[nt][r] + bs;
                    x = x*scl + sh;
                    x = (x >= 0.f) ? x : al2*x;
                    sum[r] += x * w3v;
                }
            }
        }
        #pragma unroll
        for (int r = 0; r < 4; ++r)
            #pragma unroll
            for (int d = 1; d <= 8; d <<= 1) sum[r] += __shfl_xor(sum[r], d);
        if (lm == 0) {
            float b3v = ldf(b3p, 0, f);
            #pragma unroll
            for (int r = 0; r < 4; ++r) {
                float rr = sum[r] + b3v;
                if (f) ((float*)outp)[row + r] = rr;
                else   ((u16*)outp)[row + r]  = f2b(rr);
            }
        }
    }
}

// ---------------------------------------------------------------------------
// Self-attention (unchanged from round 11 — passing; serves as the
// container-speed control dispatch: fast ~75us @ ~600GB/s, slow ~114us).
// ---------------------------------------------------------------------------
template<int QTPB>
__global__ __launch_bounds__(256) void k_sattn(
    const u16* __restrict__ Q, const u16* __restrict__ K, const u16* __restrict__ V,
    u16* __restrict__ O, const void* __restrict__ center,
    const float* __restrict__ rsinv, const int* __restrict__ flags, int bdiv)
{
    __shared__ __align__(16) u16 Vt[32*264];
    __shared__ __align__(16) u16 P[4][16*40];
    __shared__ float cxl[256], cyl[256], czl[256], rsl[256];
    int s = blockIdx.x, h = blockIdx.y;
    int t = threadIdx.x, w = t>>6, lane = t&63, lm = lane&15, q4 = lane>>4;
    int f = flags[0];
    int b = s / bdiv;
    for (int idx = t; idx < 256*8; idx += 256) {
        int k = idx >> 3, d4 = idx & 7;
        ushort4 u = *(const ushort4*)(V + ((size_t)s*KQ + k)*HID + h*32 + d4*4);
        Vt[(d4*4+0)*264 + k] = u.x;
        Vt[(d4*4+1)*264 + k] = u.y;
        Vt[(d4*4+2)*264 + k] = u.z;
        Vt[(d4*4+3)*264 + k] = u.w;
    }
    {
        int j = (b << 8) + t;
        cxl[t] = ldf(center, j*3+0, f);
        cyl[t] = ldf(center, j*3+1, f);
        czl[t] = ldf(center, j*3+2, f);
        rsl[t] = rsinv[j];
    }
    __syncthreads();
    u16* Pw = P[w];
    const u16* Kbase = K + (size_t)s*KQ*HID + h*32;
    for (int qi = 0; qi < QTPB; ++qi) {
        int qt = blockIdx.z*QTPB + qi;
        int qrow0 = qt*64 + w*16;
        s16x8 aq = *(const s16x8*)(Q + ((size_t)s*KQ + qrow0 + lm)*HID + h*32 + q4*8);
        float qx[4], qy[4], qz[4];
        if (h < 2) {
            #pragma unroll
            for (int r = 0; r < 4; ++r) {
                int q = qrow0 + q4*4 + r;
                qx[r] = cxl[q]; qy[r] = cyl[q]; qz[r] = czl[q];
            }
        }
        float S[16][4];
        #pragma unroll
        for (int kt = 0; kt < 16; ++kt) {
            s16x8 bF = *(const s16x8*)(Kbase + (size_t)(kt*16 + lm)*HID + q4*8);
            f32x4 acc = f32x4{0.f,0.f,0.f,0.f};
            acc = mfma16(aq, bF, acc);
            int key = kt*16 + lm;
            float kx = 0.f, ky = 0.f, kz = 0.f, rs_ = 1.f;
            if (h < 2) { kx = cxl[key]; ky = cyl[key]; kz = czl[key]; rs_ = rsl[key]; }
            #pragma unroll
            for (int r = 0; r < 4; ++r) {
                float sc = acc[r]*SCALE_F;
                if (h < 2) {
                    float dx = qx[r]-kx, dy = qy[r]-ky, dz = qz[r]-kz;
                    float d  = sqrtf(dx*dx + dy*dy + dz*dz);
                    if (h == 0) sc += __builtin_amdgcn_rcpf(d + 0.01f) * rs_;
                    else        sc -= d;
                }
                S[kt][r] = sc;
            }
        }
        float linv[4];
        #pragma unroll
        for (int r = 0; r < 4; ++r) {
            float m = -3.0e38f;
            #pragma unroll
            for (int kt = 0; kt < 16; ++kt) m = fmaxf(m, S[kt][r]);
            #pragma unroll
            for (int d = 1; d <= 8; d <<= 1) m = fmaxf(m, __shfl_xor(m, d));
            float sum = 0.f;
            #pragma unroll
            for (int kt = 0; kt < 16; ++kt) { float p = __expf(S[kt][r]-m); S[kt][r] = p; sum += p; }
            #pragma unroll
            for (int d = 1; d <= 8; d <<= 1) sum += __shfl_xor(sum, d);
            linv[r] = __builtin_amdgcn_rcpf(sum);
        }
        f32x4 acc[2];
        acc[0] = f32x4{0.f,0.f,0.f,0.f};
        acc[1] = f32x4{0.f,0.f,0.f,0.f};
        #pragma unroll
        for (int ks = 0; ks < 8; ++ks) {
            #pragma unroll
            for (int kk = 0; kk < 2; ++kk)
                #pragma unroll
                for (int r = 0; r < 4; ++r)
                    Pw[(q4*4+r)*40 + kk*16 + lm] = f2b(S[ks*2+kk][r]);
            s16x8 ap = *(const s16x8*)(Pw + lm*40 + q4*8);
            #pragma unroll
            for (int nt = 0; nt < 2; ++nt) {
                s16x8 bv = *(const s16x8*)(Vt + (nt*16+lm)*264 + ks*32 + q4*8);
                acc[nt] = mfma16(ap, bv, acc[nt]);
            }
        }
        #pragma unroll
        for (int nt = 0; nt < 2; ++nt)
            #pragma unroll
            for (int r = 0; r < 4; ++r)
                O[((size_t)s*KQ + qrow0 + q4*4 + r)*HID + h*32 + nt*16 + lm] = f2b(acc[nt][r] * linv[r]);
    }
}

// ---------------------------------------------------------------------------
// Cross-attention (unchanged — passing).
// ---------------------------------------------------------------------------
__global__ __launch_bounds__(256) void k_xattn(
    const u16* __restrict__ Q, const u16* __restrict__ K, const u16* __restrict__ V,
    u16* __restrict__ O, const unsigned char* __restrict__ mask)
{
    __shared__ __align__(16) u16 Kl[64*40];
    __shared__ __align__(16) u16 Vt[32*72];
    __shared__ __align__(16) u16 P[4][16*72];
    __shared__ float madd[64];
    int s = blockIdx.x, h = blockIdx.y;
    int t = threadIdx.x, w = t>>6, lane = t&63, lm = lane&15, q4 = lane>>4;
    if (t < 64) {
        const u16* src = K + ((size_t)s*64 + t)*HID + h*32;
        u16* dst = Kl + t*40;
        #pragma unroll
        for (int i = 0; i < 4; ++i) *(s16x8*)(dst + i*8) = *(const s16x8*)(src + i*8);
        madd[t] = mask[s*64 + t] ? -1.0e9f : 0.f;
    }
    for (int idx = t; idx < 64*8; idx += 256) {
        int k = idx >> 3, d4 = idx & 7;
        ushort4 u = *(const ushort4*)(V + ((size_t)s*64 + k)*HID + h*32 + d4*4);
        Vt[(d4*4+0)*72 + k] = u.x;
        Vt[(d4*4+1)*72 + k] = u.y;
        Vt[(d4*4+2)*72 + k] = u.z;
        Vt[(d4*4+3)*72 + k] = u.w;
    }
    __syncthreads();
    u16* Pw = P[w];
    for (int qt = 0; qt < 4; ++qt) {
        int qrow0 = qt*64 + w*16;
        s16x8 aq = *(const s16x8*)(Q + ((size_t)s*KQ + qrow0 + lm)*HID + h*32 + q4*8);
        float S[4][4];
        #pragma unroll
        for (int kt = 0; kt < 4; ++kt) {
            s16x8 bF = *(const s16x8*)(Kl + (kt*16+lm)*40 + q4*8);
            f32x4 acc = f32x4{0.f,0.f,0.f,0.f};
            acc = mfma16(aq, bF, acc);
            float ma = madd[kt*16 + lm];
            #pragma unroll
            for (int r = 0; r < 4; ++r) S[kt][r] = acc[r]*SCALE_F + ma;
        }
        float linv[4];
        #pragma unroll
        for (int r = 0; r < 4; ++r) {
            float m = -3.0e38f;
            #pragma unroll
            for (int kt = 0; kt < 4; ++kt) m = fmaxf(m, S[kt][r]);
            #pragma unroll
            for (int d = 1; d <= 8; d <<= 1) m = fmaxf(m, __shfl_xor(m, d));
            float sum = 0.f;
            #pragma unroll
            for (int kt = 0; kt < 4; ++kt) { float p = __expf(S[kt][r]-m); S[kt][r] = p; sum += p; }
            #pragma unroll
            for (int d = 1; d <= 8; d <<= 1) sum += __shfl_xor(sum, d);
            linv[r] = __builtin_amdgcn_rcpf(sum);
        }
        #pragma unroll
        for (int kt = 0; kt < 4; ++kt)
            #pragma unroll
            for (int r = 0; r < 4; ++r)
                Pw[(q4*4+r)*72 + kt*16 + lm] = f2b(S[kt][r]);
        #pragma unroll
        for (int nt = 0; nt < 2; ++nt) {
            f32x4 acc = f32x4{0.f,0.f,0.f,0.f};
            #pragma unroll
            for (int ks = 0; ks < 2; ++ks) {
                s16x8 ap = *(const s16x8*)(Pw + lm*72 + ks*32 + q4*8);
                s16x8 bv = *(const s16x8*)(Vt + (nt*16+lm)*72 + ks*32 + q4*8);
                acc = mfma16(ap, bv, acc);
            }
            #pragma unroll
            for (int r = 0; r < 4; ++r)
                O[((size_t)s*KQ + qrow0 + q4*4 + r)*HID + h*32 + nt*16 + lm] = f2b(acc[r] * linv[r]);
        }
    }
}

// ---------------------------------------------------------------------------
extern "C" void kernel_launch(void* const* d_in, const int* in_sizes, int n_in,
                              void* d_out, int out_size, void* d_ws, size_t ws_size,
                              hipStream_t stream)
{
    (void)n_in;
    if (ws_size < (size_t)NEEDF * 4) {
        fprintf(stderr, "kernel_launch: ws too small: have %zu need %zu\n",
                ws_size, (size_t)NEEDF * 4);
        hipMemsetAsync(d_out, 0, (size_t)out_size * 2, stream);
        return;
    }
    float* F = (float*)d_ws;
    u16*   U = (u16*)d_ws;
    int* flags = (int*)d_ws;
    u16* WB     = U + (size_t)OFF_WB*2;
    u16* langb  = U + (size_t)OFF_LANGB*2;
    u16* detrb  = U + (size_t)OFF_KB*2;
    u16* featsb = U + (size_t)OFF_FEATSB*2;
    u16* x2b    = U + (size_t)OFF_FAB*2;
    u16* fAb    = U + (size_t)OFF_FAB*2;
    u16* x1b    = U + (size_t)OFF_VB*2;
    u16* Qb     = U + (size_t)OFF_QB*2;
    u16* Kb     = U + (size_t)OFF_KB*2;
    u16* Vb     = U + (size_t)OFF_VB*2;
    float* rsinv = F + OFF_ROWS;
    unsigned char* mask8 = (unsigned char*)(F + OFF_MASK);

    k_detect<<<1, 256, 0, stream>>>((const unsigned*)d_in[8],
                                    (const unsigned*)d_in[48], flags);
    k_mask_canon<<<64, 256, 0, stream>>>((const unsigned char*)d_in[48], flags, mask8);

    CvTab ct;
    {
        const int idx[14] = {3,18,20,21,22,23,30,31,32,33,40,43,1,2};
        const unsigned long long dst[14] = {
            (unsigned long long)OFF_WB*2 + WB_FCW1, (unsigned long long)OFF_WB*2 + WB_FCW2,
            (unsigned long long)OFF_WB*2 + WB_SAWQ, (unsigned long long)OFF_WB*2 + WB_SAWK,
            (unsigned long long)OFF_WB*2 + WB_SAWV, (unsigned long long)OFF_WB*2 + WB_SAWO,
            (unsigned long long)OFF_WB*2 + WB_CAWQ, (unsigned long long)OFF_WB*2 + WB_CAWK,
            (unsigned long long)OFF_WB*2 + WB_CAWV, (unsigned long long)OFF_WB*2 + WB_CAWO,
            (unsigned long long)OFF_WB*2 + WB_MW1,  (unsigned long long)OFF_WB*2 + WB_MW2,
            (unsigned long long)OFF_KB*2,           (unsigned long long)OFF_LANGB*2 };
        const int bs[15] = {0,144,160,192,224,256,288,320,352,384,416,432,448,5056,7104};
        for (int e = 0; e < 14; ++e) { ct.src[e] = d_in[idx[e]]; ct.dst[e] = dst[e]; }
        for (int e = 0; e < 15; ++e) ct.bstart[e] = bs[e];
    }
    k_convAll<<<7104, 256, 0, stream>>>(ct, U, flags);

    k_rowsum<<<4096, 256, 0, stream>>>(d_in[0], rsinv, flags);

    const void* N0 = nullptr;
    const u16*  NU = nullptr;

    // features_concat
    k_gemm<1,false,false><<<64, 256, 0, stream>>>(detrb, WB+WB_FCW1, x1b, 1152,
        d_in[4], d_in[5], d_in[6], d_in[7], d_in[8], d_in[17], N0, N0, nullptr, flags, 0);
    k_gemm<0,false,false><<<64, 256, 0, stream>>>(x1b, WB+WB_FCW2, x2b, 128,
        d_in[19], N0,N0,N0,N0,N0, N0, N0, nullptr, flags, 0);

    // sa0
    k_gemmN<false><<<dim3(64,3), 256, 0, stream>>>(x2b,
        WB+WB_SAWQ, WB+WB_SAWK, WB+WB_SAWV, Qb, Kb, Vb,
        d_in[24], d_in[25], d_in[26], flags, 0);
    k_sattn<1><<<dim3(16,4,4), 256, 0, stream>>>(Qb, Kb, Vb, Qb, d_in[0], rsinv, flags, 1);
    k_gemm<3,false,false><<<64, 256, 0, stream>>>(Qb, WB+WB_SAWO, featsb, 128,
        d_in[27], N0,N0,N0,N0,N0, d_in[29], d_in[28], x2b, flags, 0);

    // ca0
    k_gemm<0,true,false><<<1024, 256, 0, stream>>>(featsb, WB+WB_CAWQ, Qb, 128,
        d_in[34], N0,N0,N0,N0,N0, N0, N0, nullptr, flags, 0);
    k_gemmN<false><<<dim3(256,2), 256, 0, stream>>>(langb,
        WB+WB_CAWK, WB+WB_CAWV, nullptr, Kb, Vb, nullptr,
        d_in[35], d_in[36], nullptr, flags, 0);
    k_xattn<<<dim3(256,4), 256, 0, stream>>>(Qb, Kb, Vb, Qb, mask8);

    // chain4: ca0 O-proj+resid(featsb,BCAST)+LN -> fAb, then sa1 Q/K/V projections
    k_chain<1><<<1024, 256, 0, stream>>>(
        Qb, WB+WB_CAWO, featsb, fAb,
        d_in[37], d_in[39], d_in[38],
        WB+WB_SAWQ+16384, d_in[24], Qb,
        WB+WB_SAWK+16384, d_in[25], Kb,
        WB+WB_SAWV+16384, d_in[26], Vb,
        N0,N0,N0,N0,N0, N0,N0,N0,N0,N0, N0, N0, nullptr,
        flags, 0, 128, 1);

    // sa1
    k_sattn<4><<<dim3(256,4,1), 256, 0, stream>>>(Qb, Kb, Vb, Qb, d_in[0], rsinv, flags, 16);

    // chain2: sa1 O-proj+resid(fAb)+LN -> fAb, then ca1 Q projection
    k_chain<0><<<1024, 256, 0, stream>>>(
        Qb, WB+WB_SAWO+16384, fAb, fAb,
        d_in[27], d_in[29], d_in[28],
        WB+WB_CAWQ+16384, d_in[34], Qb,
        NU, N0, nullptr, NU, N0, nullptr,
        N0,N0,N0,N0,N0, N0,N0,N0,N0,N0, N0, N0, nullptr,
        flags, 128, 128, 0);

    // ca1
    k_gemmN<false><<<dim3(256,2), 256, 0, stream>>>(langb,
        WB+WB_CAWK+16384, WB+WB_CAWV+16384, nullptr, Kb, Vb, nullptr,
        d_in[35], d_in[36], nullptr, flags, 128);
    k_xattn<<<dim3(256,4), 256, 0, stream>>>(Qb, Kb, Vb, Qb, mask8);

    // tail: ca1 O-proj+resid(fAb)+LN (no global write), mW1+BN/PReLU,
    // mW2+BN/PReLU, dot(w3)+b3 -> d_out
    k_chain<2><<<1024, 256, 0, stream>>>(
        Qb, WB+WB_CAWO+16384, fAb, nullptr,
        d_in[37], d_in[39], d_in[38],
        WB+WB_MW1, d_in[41], nullptr,
        WB+WB_MW2, d_in[44], nullptr,
        NU, N0, nullptr,
        d_in[9], d_in[10], d_in[11], d_in[12], d_in[42],
        d_in[13], d_in[14], d_in[15], d_in[16], d_in[45],
        d_in[46], d_in[47], d_out,
        flags, 128, 0, 0);
}